// Round 1
// 230.274 us; speedup vs baseline: 1.0611x; 1.0611x over previous
//
#include <hip/hip_runtime.h>

constexpr int kB  = 16;
constexpr int kLM = 1024;
constexpr int kLX = 1024;
constexpr int kD  = 768;

using short8 = __attribute__((ext_vector_type(8))) short;
using f32x4  = __attribute__((ext_vector_type(4))) float;

__device__ __forceinline__ unsigned short f2bf(float f) {
    unsigned u = __float_as_uint(f);
    u = (u + 0x7FFF + ((u >> 16) & 1)) >> 16;   // RNE
    return (unsigned short)u;
}
__device__ __forceinline__ float bf2f(unsigned short h) {
    return __uint_as_float(((unsigned)h) << 16);
}

// async 16B global->LDS copy; dst must be wave-uniform base + lane*16.
__device__ __forceinline__ void gl_lds16(const unsigned short* g, unsigned short* l) {
    auto gp = (const __attribute__((address_space(1))) unsigned int*)g;
    auto lp = (__attribute__((address_space(3))) unsigned int*)l;
    __builtin_amdgcn_global_load_lds(gp, lp, 16, 0, 0);
}

// cvt 8 fp32 -> one 16B bf16 chunk
__device__ __forceinline__ void writeChunk(unsigned short* dst, float4 lo, float4 hi) {
    union { short8 v; unsigned short u[8]; } o;
    o.u[0] = f2bf(lo.x); o.u[1] = f2bf(lo.y); o.u[2] = f2bf(lo.z); o.u[3] = f2bf(lo.w);
    o.u[4] = f2bf(hi.x); o.u[5] = f2bf(hi.y); o.u[6] = f2bf(hi.z); o.u[7] = f2bf(hi.w);
    *(short8*)dst = o.v;
}

// inverse XOR swizzle: LDS chunk index -> global (row, kseg) element offset
__device__ __forceinline__ size_t chunk_off(int c, int K) {
    int sr = c >> 3, s = c & 7;
    int tt = s ^ (sr & 7);
    int r  = sr * 2 + (tt >> 2);
    int q  = tt & 3;
    return (size_t)r * K + q * 8;
}

// ---------------------------------------------------------------------------
// Transpose + convert: xT[b][d][l] = bf16(x[b][l][d])
// ---------------------------------------------------------------------------
__global__ __launch_bounds__(256) void transpose_cvt_kernel(
    const float* __restrict__ x, unsigned short* __restrict__ xT) {
    __shared__ float tile[64][65];
    const int b  = blockIdx.z;
    const int l0 = blockIdx.x * 64;
    const int d0 = blockIdx.y * 64;
    const int t  = threadIdx.x;
    const int tx = t & 15, ty = t >> 4;
    const float* xb = x + ((size_t)b * kLX + l0) * kD + d0;
#pragma unroll
    for (int p = 0; p < 4; ++p) {
        int r = p * 16 + ty;
        float4 v = *(const float4*)(xb + (size_t)r * kD + tx * 4);
        *(float4*)&tile[r][tx * 4] = v;
    }
    __syncthreads();
    unsigned short* xTb = xT + ((size_t)b * kD + d0) * kLX + l0;
#pragma unroll
    for (int p = 0; p < 4; ++p) {
        int dr = p * 16 + ty;
        ushort4 o;
        o.x = f2bf(tile[tx * 4 + 0][dr]);
        o.y = f2bf(tile[tx * 4 + 1][dr]);
        o.z = f2bf(tile[tx * 4 + 2][dr]);
        o.w = f2bf(tile[tx * 4 + 3][dr]);
        *(ushort4*)(xTb + (size_t)dr * kLX + tx * 4) = o;
    }
}

// ---------------------------------------------------------------------------
// Two-tensor fp32 -> bf16 convert (main, W) in one launch. 8 elems/thread.
// ---------------------------------------------------------------------------
__global__ __launch_bounds__(256) void cvt2_kernel(
    const float* __restrict__ a, unsigned short* __restrict__ oa, int na8,
    const float* __restrict__ b, unsigned short* __restrict__ ob, int nb8) {
    int i = blockIdx.x * 256 + threadIdx.x;
    const float* src;
    unsigned short* dst;
    if (i < na8) {
        src = a + (size_t)i * 8; dst = oa + (size_t)i * 8;
    } else {
        int j = i - na8;
        if (j >= nb8) return;
        src = b + (size_t)j * 8; dst = ob + (size_t)j * 8;
    }
    float4 lo = *(const float4*)src;
    float4 hi = *(const float4*)(src + 4);
    writeChunk(dst, lo, hi);
}

// ---------------------------------------------------------------------------
// NT bf16 MFMA GEMM, 128x128 tile, BK=32, 256 thr (2x2 waves), 4x4 MFMA/wave.
// C[i][j] = sum_k A[i][k]*B[j][k]. XOR-swizzled 16B-chunk LDS (conflict-free).
//
// T4 counted-vmcnt pipeline (m218): 3 LDS buffers, depth-2 prefetch of
// global_load_lds, raw s_barrier + literal s_waitcnt vmcnt(8/4/0) -- loads
// for tiles t+1,t+2 stay in flight ACROSS barriers; vmcnt never drains to 0
// in the main loop. Hazard proof:
//   BAR1 (after own vmcnt(8)): everyone's tile-t loads landed -> safe reads.
//   BAR2 (after MFMA): lgkm drained before MFMA, so passing BAR2 => all
//   waves' reads of buf[t%3] complete; stage of t+3 (same buffer) is issued
//   only after BAR2 -> no write-after-read race.
//
// XCD swizzle: 1D grid, xcd = wgid&7, batch = grp*8+xcd -> all tiles of a
// batch (<=3 MB working set) pin to one XCD's 4 MB L2.
//
// SYMM: A==B (G = xT xT^T symmetric): compute only bi>=bj tiles; epilogue
// writes the mirrored tile too (r-values contiguous along mirrored rows ->
// coalesced ushort4 stores).
// ---------------------------------------------------------------------------
template <bool SYMM>
__global__ __launch_bounds__(256) void gemm_nt_kernel(
    const unsigned short* __restrict__ A, const unsigned short* __restrict__ B,
    unsigned short* __restrict__ C, int M, int N, int K,
    long sA, long sB, long sC, int gx, int gy) {
    __shared__ unsigned short Asm[3][128 * 32];   // 3 x 8 KB
    __shared__ unsigned short Bsm[3][128 * 32];   // 3 x 8 KB   (48 KB total)

    // XCD-aware block decode (batch -> XCD pinning)
    const int wgid = blockIdx.x;
    const int xcd  = wgid & 7;
    const int kk   = wgid >> 3;
    const int tpb  = gx * gy;           // tiles per batch
    const int grp  = kk / tpb;          // 0 .. B/8-1
    const int til  = kk - grp * tpb;
    const int b    = grp * 8 + xcd;
    const int bi   = til % gx;
    const int bj   = til / gx;
    if (SYMM && bi < bj) return;        // uniform early-exit, no barrier hazard
    const int i0 = bi * 128, j0 = bj * 128;

    const int t    = threadIdx.x;
    const int wave = t >> 6, lane = t & 63;
    const int wr = (wave >> 1) * 64, wc = (wave & 1) * 64;
    const int quad = lane >> 4, l15 = lane & 15;

    const unsigned short* Ab = A + (size_t)b * sA + (size_t)i0 * K;
    const unsigned short* Bb = B + (size_t)b * sB + (size_t)j0 * K;

    const int c0 = t, c1 = t + 256;
    const size_t off0 = chunk_off(c0, K);
    const size_t off1 = chunk_off(c1, K);

    const int sfr  = ((l15 & 1) * 4 + quad) ^ ((l15 >> 1) & 7);
    const int aOff = wr * 32 + (l15 >> 1) * 64 + sfr * 8;
    const int bOff = wc * 32 + (l15 >> 1) * 64 + sfr * 8;

    f32x4 acc[4][4];
    const f32x4 z = {0.f, 0.f, 0.f, 0.f};
#pragma unroll
    for (int i = 0; i < 4; ++i)
#pragma unroll
        for (int j = 0; j < 4; ++j) acc[i][j] = z;

    const int T = K >> 5;

    // ---- prologue: stage tiles 0 and 1 (8 loads in flight) ----
    gl_lds16(Ab + off0, Asm[0] + c0 * 8);
    gl_lds16(Ab + off1, Asm[0] + c1 * 8);
    gl_lds16(Bb + off0, Bsm[0] + c0 * 8);
    gl_lds16(Bb + off1, Bsm[0] + c1 * 8);
    if (T > 1) {
        gl_lds16(Ab + off0 + 32, Asm[1] + c0 * 8);
        gl_lds16(Ab + off1 + 32, Asm[1] + c1 * 8);
        gl_lds16(Bb + off0 + 32, Bsm[1] + c0 * 8);
        gl_lds16(Bb + off1 + 32, Bsm[1] + c1 * 8);
    }

    int cur = 0;
    for (int kt = 0; kt < T; ++kt) {
        if (kt + 2 < T) {
            int nb = cur + 2; if (nb >= 3) nb -= 3;
            const size_t k = (size_t)(kt + 2) << 5;
            gl_lds16(Ab + off0 + k, Asm[nb] + c0 * 8);
            gl_lds16(Ab + off1 + k, Asm[nb] + c1 * 8);
            gl_lds16(Bb + off0 + k, Bsm[nb] + c0 * 8);
            gl_lds16(Bb + off1 + k, Bsm[nb] + c1 * 8);
            // tiles kt+1 (4) and kt+2 (4) stay in flight; wait only for kt
            asm volatile("s_waitcnt vmcnt(8)" ::: "memory");
        } else if (kt + 1 < T) {
            asm volatile("s_waitcnt vmcnt(4)" ::: "memory");
        } else {
            asm volatile("s_waitcnt vmcnt(0)" ::: "memory");
        }
        __builtin_amdgcn_s_barrier();           // BAR1: tile kt fully staged
        asm volatile("" ::: "memory");

        const unsigned short* aP = Asm[cur] + aOff;
        const unsigned short* bP = Bsm[cur] + bOff;
        short8 af[4], bg[4];
#pragma unroll
        for (int i = 0; i < 4; ++i) af[i] = *(const short8*)(aP + i * 512);
#pragma unroll
        for (int j = 0; j < 4; ++j) bg[j] = *(const short8*)(bP + j * 512);
        __builtin_amdgcn_s_setprio(1);
#pragma unroll
        for (int i = 0; i < 4; ++i)
#pragma unroll
            for (int j = 0; j < 4; ++j)
                acc[i][j] = __builtin_amdgcn_mfma_f32_16x16x32_bf16(
                    af[i], bg[j], acc[i][j], 0, 0, 0);
        __builtin_amdgcn_s_setprio(0);
        asm volatile("" ::: "memory");
        __builtin_amdgcn_s_barrier();           // BAR2: reads of buf[cur] done
        cur = cur + 1; if (cur == 3) cur = 0;
    }

    // C/D layout: col = lane&15, row = quad*4 + reg  [m89/m91 verified]
    unsigned short* Cb = C + (size_t)b * sC + (size_t)(i0 + wr) * N + j0 + wc;
#pragma unroll
    for (int i = 0; i < 4; ++i)
#pragma unroll
        for (int j = 0; j < 4; ++j)
#pragma unroll
            for (int r = 0; r < 4; ++r)
                Cb[(size_t)(i * 16 + quad * 4 + r) * N + j * 16 + l15] =
                    f2bf(acc[i][j][r]);

    if (SYMM && bi > bj) {
        // mirror tile: C[j0+c][i0+r] = acc value; r-values contiguous -> ushort4
        unsigned short* Cm = C + (size_t)b * sC + (size_t)(j0 + wc) * N + i0 + wr;
#pragma unroll
        for (int i = 0; i < 4; ++i)
#pragma unroll
            for (int j = 0; j < 4; ++j) {
                ushort4 o;
                o.x = f2bf(acc[i][j][0]);
                o.y = f2bf(acc[i][j][1]);
                o.z = f2bf(acc[i][j][2]);
                o.w = f2bf(acc[i][j][3]);
                *(ushort4*)(Cm + (size_t)(j * 16 + l15) * N + i * 16 + quad * 4) = o;
            }
    }
}

// ---------------------------------------------------------------------------
// Fused beta + pooled. Grid (64,16): 4 blocks/CU. Wave handles 4 rows.
// Cross-wave LDS pre-reduction -> 1 atomicAdd per (s,lane) per block.
// ---------------------------------------------------------------------------
__global__ __launch_bounds__(256) void pool_kernel(
    const float* __restrict__ mainp, const unsigned short* __restrict__ Aout,
    const float* __restrict__ w, float* __restrict__ out) {
    __shared__ float red[4][24][64];   // 24 KB
    const int b     = blockIdx.y;
    const int chunk = blockIdx.x;           // 64 chunks of 16 rows
    const int t     = threadIdx.x;
    const int wave  = t >> 6, lane = t & 63;
    float w1[12], w2[12], ps[12], pm[12];
#pragma unroll
    for (int s = 0; s < 12; ++s) {
        w1[s] = w[s * 64 + lane];
        w2[s] = w[kD + s * 64 + lane];
        ps[s] = 0.f; pm[s] = 0.f;
    }
#pragma unroll
    for (int rr = 0; rr < 4; ++rr) {
        const int row = chunk * 16 + rr * 4 + wave;
        const float* mr = mainp + ((size_t)b * kLM + row) * kD;
        const unsigned short* ar = Aout + ((size_t)b * kLM + row) * kD;
        float sv[12], mv[12], acc = 0.f;
#pragma unroll
        for (int s = 0; s < 12; ++s) {
            float m_ = mr[s * 64 + lane];
            float a_ = bf2f(ar[s * 64 + lane]);
            sv[s] = m_ - a_;
            mv[s] = m_ * a_;
            acc += sv[s] * w1[s] + mv[s] * w2[s];
        }
#pragma unroll
        for (int off = 32; off; off >>= 1) acc += __shfl_xor(acc, off);
#pragma unroll
        for (int s = 0; s < 12; ++s) { ps[s] += acc * sv[s]; pm[s] += acc * mv[s]; }
    }
#pragma unroll
    for (int s = 0; s < 12; ++s) {
        red[wave][s][lane]      = ps[s];
        red[wave][12 + s][lane] = pm[s];
    }
    __syncthreads();
    float* ob = out + (size_t)b * 2 * kD;
    for (int v = t; v < 24 * 64; v += 256) {
        const int sl = v >> 6, ln = v & 63;
        const float sum = red[0][sl][ln] + red[1][sl][ln] +
                          red[2][sl][ln] + red[3][sl][ln];
        const int d = (sl < 12) ? sl * 64 + ln : kD + (sl - 12) * 64 + ln;
        atomicAdd(&ob[d], sum);
    }
}

extern "C" void kernel_launch(void* const* d_in, const int* in_sizes, int n_in,
                              void* d_out, int out_size, void* d_ws, size_t ws_size,
                              hipStream_t stream) {
    const float* mainp = (const float*)d_in[0];  // (B, LM, D)
    const float* x     = (const float*)d_in[1];  // (B, LX, D)
    const float* W     = (const float*)d_in[2];  // (D, D)
    const float* w     = (const float*)d_in[3];  // (2D, 1)
    float* out = (float*)d_out;                  // (B, 2D)

    char* p = (char*)d_ws;
    unsigned short* xT  = (unsigned short*)p; p += (size_t)kB * kD * kLX * 2;
    unsigned short* G   = (unsigned short*)p; p += (size_t)kB * kD * kD * 2;
    unsigned short* Mt  = (unsigned short*)p; p += (size_t)kB * kD * kD * 2;
    unsigned short* Ao  = (unsigned short*)p; p += (size_t)kB * kLM * kD * 2;
    unsigned short* Wbf = (unsigned short*)p; p += (size_t)kD * kD * 2;
    unsigned short* mainBF = xT;  // alias: xT dead after GEMM1, same size

    hipMemsetAsync(out, 0, (size_t)kB * 2 * kD * sizeof(float), stream);

    transpose_cvt_kernel<<<dim3(kLX / 64, kD / 64, kB), 256, 0, stream>>>(x, xT);

    // G[b] = xT[b] @ xT[b]^T  (symmetric: 21/36 tiles computed, mirror-written)
    gemm_nt_kernel<true><<<dim3(kB * 36), 256, 0, stream>>>(
        xT, xT, G, kD, kD, kLX, (long)kD * kLX, (long)kD * kLX, (long)kD * kD,
        6, 6);

    // main -> bf16 (into xT's space; xT is dead now) and W -> bf16
    cvt2_kernel<<<dim3((kB * kLM * kD / 8 + kD * kD / 8 + 255) / 256), 256, 0,
                  stream>>>(mainp, mainBF, kB * kLM * kD / 8, W, Wbf,
                            kD * kD / 8);

    // Mt[b] = G[b] @ W^T  (Mt^T = W @ G since G symmetric)
    gemm_nt_kernel<false><<<dim3(kB * 36), 256, 0, stream>>>(
        G, Wbf, Mt, kD, kD, kD, (long)kD * kD, 0L, (long)kD * kD, 6, 6);

    // A[b] = mainBF[b] @ Mt[b]^T
    gemm_nt_kernel<false><<<dim3(kB * 48), 256, 0, stream>>>(
        mainBF, Mt, Ao, kLM, kD, kD, (long)kLM * kD, (long)kD * kD,
        (long)kLM * kD, 8, 6);

    pool_kernel<<<dim3(kLM / 16, kB), 256, 0, stream>>>(mainp, Ao, w, out);
}